// Round 2
// baseline (449.982 us; speedup 1.0000x reference)
//
#include <hip/hip_runtime.h>
#include <cstdint>
#include <cstddef>

#define S_LEN 4096
#define B_SZ 16
#define H2D 1024
#define P_PER_B 256     // partial accumulators per batch in pass 2

__device__ __forceinline__ float dot4(float4 a, float4 b) {
    return a.x * b.x + a.y * b.y + a.z * b.z + a.w * b.w;
}
__device__ __forceinline__ void axpy4(float4& acc, float w, float4 v) {
    acc.x += w * v.x; acc.y += w * v.y; acc.z += w * v.z; acc.w += w * v.w;
}

// altered[b][i] = attn_b[i] + sum_j state[b][j]*attn_w[i][j]; one wave per row i.
// Coalesced: lane loads float4 at index lane+64*j (contiguous 1KB per instr).
__global__ __launch_bounds__(256) void k_altered(const float* __restrict__ state,
                                                 const float* __restrict__ attn_w,
                                                 const float* __restrict__ attn_b,
                                                 float* __restrict__ altered) {
    const int i = (blockIdx.x * 256 + threadIdx.x) >> 6;  // 0..1023
    const int lane = threadIdx.x & 63;
    const float4* w4 = (const float4*)(attn_w + (size_t)i * H2D);
    float4 r[4];
#pragma unroll
    for (int j = 0; j < 4; ++j) r[j] = w4[lane + 64 * j];
    const float bias = attn_b[i];
    for (int b = 0; b < B_SZ; ++b) {
        const float4* s4 = (const float4*)(state + b * H2D);
        float p = 0.f;
#pragma unroll
        for (int j = 0; j < 4; ++j) p += dot4(r[j], s4[lane + 64 * j]);
#pragma unroll
        for (int off = 32; off; off >>= 1) p += __shfl_xor(p, off, 64);
        if (lane == 0) altered[b * H2D + i] = p + bias;
    }
}

// Pass 1: w_raw[b][s] = dot(altered[b], enc[s][b]). Pure stream over enc (256 MB).
// grid (64, B) x 256 thr; wave slot owns 16 contiguous rows, unroll 4.
__global__ __launch_bounds__(256) void k_pass1(const float* __restrict__ enc,
                                               const float* __restrict__ altered,
                                               float* __restrict__ w_raw) {
    const int b = blockIdx.y;
    const int wave = threadIdx.x >> 6, lane = threadIdx.x & 63;
    const int slot = blockIdx.x * 4 + wave;  // 0..255
    const float4* a4p = (const float4*)(altered + b * H2D);
    float4 af[4];
#pragma unroll
    for (int j = 0; j < 4; ++j) af[j] = a4p[lane + 64 * j];
    const int s0 = slot * 16;
    for (int k = 0; k < 16; k += 4) {
        float4 e[4][4];
#pragma unroll
        for (int r = 0; r < 4; ++r) {
            const float4* e4 = (const float4*)(enc + ((size_t)(s0 + k + r) * B_SZ + b) * H2D);
#pragma unroll
            for (int j = 0; j < 4; ++j) e[r][j] = e4[lane + 64 * j];
        }
        float p[4];
#pragma unroll
        for (int r = 0; r < 4; ++r) {
            p[r] = 0.f;
#pragma unroll
            for (int j = 0; j < 4; ++j) p[r] += dot4(af[j], e[r][j]);
        }
#pragma unroll
        for (int off = 32; off; off >>= 1) {
#pragma unroll
            for (int r = 0; r < 4; ++r) p[r] += __shfl_xor(p[r], off, 64);
        }
        if (lane == 0) {
#pragma unroll
            for (int r = 0; r < 4; ++r) w_raw[b * S_LEN + s0 + k + r] = p[r];
        }
    }
}

// Softmax over S per batch; writes normalized weights straight to out_nw.
__global__ __launch_bounds__(1024) void k_softmax(const float* __restrict__ w_raw,
                                                  float* __restrict__ out_nw) {
    const int b = blockIdx.x, t = threadIdx.x;
    const int wave = t >> 6, lane = t & 63;
    __shared__ float sm[16], ss[16], sbc[2];
    float4 v = ((const float4*)(w_raw + b * S_LEN))[t];
    float m = fmaxf(fmaxf(v.x, v.y), fmaxf(v.z, v.w));
#pragma unroll
    for (int off = 32; off; off >>= 1) m = fmaxf(m, __shfl_xor(m, off, 64));
    if (lane == 0) sm[wave] = m;
    __syncthreads();
    if (t == 0) {
        float M = sm[0];
#pragma unroll
        for (int i = 1; i < 16; ++i) M = fmaxf(M, sm[i]);
        sbc[0] = M;
    }
    __syncthreads();
    const float M = sbc[0];
    float4 e;
    e.x = __expf(v.x - M); e.y = __expf(v.y - M);
    e.z = __expf(v.z - M); e.w = __expf(v.w - M);
    float s = e.x + e.y + e.z + e.w;
#pragma unroll
    for (int off = 32; off; off >>= 1) s += __shfl_xor(s, off, 64);
    if (lane == 0) ss[wave] = s;
    __syncthreads();
    if (t == 0) {
        float Z = 0.f;
#pragma unroll
        for (int i = 0; i < 16; ++i) Z += ss[i];
        sbc[1] = 1.f / Z;
    }
    __syncthreads();
    const float iZ = sbc[1];
    ((float4*)(out_nw + b * S_LEN))[t] = make_float4(e.x * iZ, e.y * iZ, e.z * iZ, e.w * iZ);
}

// Pass 2: partial weighted sums over s-chunks. Pure stream over enc (256 MB).
// grid (64, B) x 256 thr; wave slot owns 16 rows -> one partial vector of 1024.
__global__ __launch_bounds__(256) void k_pass2(const float* __restrict__ enc,
                                               const float* __restrict__ nw,
                                               float* __restrict__ pacc) {
    const int b = blockIdx.y;
    const int wave = threadIdx.x >> 6, lane = threadIdx.x & 63;
    const int slot = blockIdx.x * 4 + wave;  // 0..255
    float4 acc[4];
#pragma unroll
    for (int j = 0; j < 4; ++j) acc[j] = make_float4(0.f, 0.f, 0.f, 0.f);
    const int s0 = slot * 16;
    for (int k = 0; k < 16; k += 4) {
        float4 e[4][4];
        float w[4];
#pragma unroll
        for (int r = 0; r < 4; ++r) {
            const int s = s0 + k + r;
            const float4* e4 = (const float4*)(enc + ((size_t)s * B_SZ + b) * H2D);
#pragma unroll
            for (int j = 0; j < 4; ++j) e[r][j] = e4[lane + 64 * j];
            w[r] = nw[b * S_LEN + s];
        }
#pragma unroll
        for (int r = 0; r < 4; ++r)
#pragma unroll
            for (int j = 0; j < 4; ++j) axpy4(acc[j], w[r], e[r][j]);
    }
    float4* o = (float4*)(pacc + (size_t)(b * P_PER_B + slot) * H2D);
#pragma unroll
    for (int j = 0; j < 4; ++j) o[lane + 64 * j] = acc[j];
}

// Combine stage 1: 256 partials -> 16 per batch. grid 256 blocks x 256 thr.
__global__ __launch_bounds__(256) void k_comb1(const float* __restrict__ pacc,
                                               float* __restrict__ pacc2) {
    const int b = blockIdx.x >> 4, pg = blockIdx.x & 15, t = threadIdx.x;  // t = float4 col
    float4 s = make_float4(0.f, 0.f, 0.f, 0.f);
#pragma unroll
    for (int i = 0; i < 16; ++i) {
        const float4 v = ((const float4*)(pacc + (size_t)(b * P_PER_B + pg * 16 + i) * H2D))[t];
        s.x += v.x; s.y += v.y; s.z += v.z; s.w += v.w;
    }
    ((float4*)(pacc2 + (size_t)(b * 16 + pg) * H2D))[t] = s;
}

// Combine stage 2: 16 -> 1 per batch. grid 64 blocks x 64 thr.
__global__ __launch_bounds__(64) void k_comb2(const float* __restrict__ pacc2,
                                              float* __restrict__ out_attn) {
    const int b = blockIdx.x >> 2;
    const int col = (blockIdx.x & 3) * 64 + threadIdx.x;  // float4 col 0..255
    float4 s = make_float4(0.f, 0.f, 0.f, 0.f);
#pragma unroll
    for (int i = 0; i < 16; ++i) {
        const float4 v = ((const float4*)(pacc2 + (size_t)(b * 16 + i) * H2D))[col];
        s.x += v.x; s.y += v.y; s.z += v.z; s.w += v.w;
    }
    ((float4*)(out_attn + b * H2D))[col] = s;
}

extern "C" void kernel_launch(void* const* d_in, const int* in_sizes, int n_in,
                              void* d_out, int out_size, void* d_ws, size_t ws_size,
                              hipStream_t stream) {
    const float* enc    = (const float*)d_in[0];  // [S, B, 2H]
    const float* state  = (const float*)d_in[1];  // [B, 2H]
    // d_in[2] previous_attention, d_in[5] time_w, d_in[6] time_b: dead branch, unused
    const float* attn_w = (const float*)d_in[3];  // [2H, 2H]
    const float* attn_b = (const float*)d_in[4];  // [2H]

    float* ws = (float*)d_ws;
    float* altered = ws;                       // 16384 floats
    float* w_raw   = ws + 16384;               // 65536
    float* pacc    = ws + 16384 + 65536;       // 16*256*1024 = 4194304 (16 MB)
    float* pacc2   = pacc + (size_t)B_SZ * P_PER_B * H2D;  // 16*16*1024 = 262144 (1 MB)

    float* out_attn = (float*)d_out;               // [B, 2H]
    float* out_nw   = (float*)d_out + B_SZ * H2D;  // [B, S]

    hipLaunchKernelGGL(k_altered, dim3(256), dim3(256), 0, stream,
                       state, attn_w, attn_b, altered);
    hipLaunchKernelGGL(k_pass1, dim3(64, B_SZ), dim3(256), 0, stream,
                       enc, altered, w_raw);
    hipLaunchKernelGGL(k_softmax, dim3(B_SZ), dim3(1024), 0, stream,
                       w_raw, out_nw);
    hipLaunchKernelGGL(k_pass2, dim3(64, B_SZ), dim3(256), 0, stream,
                       enc, out_nw, pacc);
    hipLaunchKernelGGL(k_comb1, dim3(256), dim3(256), 0, stream,
                       pacc, pacc2);
    hipLaunchKernelGGL(k_comb2, dim3(64), dim3(64), 0, stream,
                       pacc2, out_attn);
}

// Round 3
// 415.820 us; speedup vs baseline: 1.0822x; 1.0822x over previous
//
#include <hip/hip_runtime.h>
#include <cstdint>
#include <cstddef>

#define S_LEN 4096
#define B_SZ 16
#define H2D 1024
#define P_PER_B 256     // one partial per wave-slot per batch

__device__ __forceinline__ float dot4(float4 a, float4 b) {
    return a.x * b.x + a.y * b.y + a.z * b.z + a.w * b.w;
}
__device__ __forceinline__ void axpy4(float4& acc, float w, float4 v) {
    acc.x += w * v.x; acc.y += w * v.y; acc.z += w * v.z; acc.w += w * v.w;
}

// altered[b][i] = attn_b[i] + sum_j state[b][j]*attn_w[i][j]; one wave per row i.
__global__ __launch_bounds__(256) void k_altered(const float* __restrict__ state,
                                                 const float* __restrict__ attn_w,
                                                 const float* __restrict__ attn_b,
                                                 float* __restrict__ altered) {
    const int i = (blockIdx.x * 256 + threadIdx.x) >> 6;  // 0..1023
    const int lane = threadIdx.x & 63;
    const float4* w4 = (const float4*)(attn_w + (size_t)i * H2D);
    float4 r[4];
#pragma unroll
    for (int j = 0; j < 4; ++j) r[j] = w4[lane + 64 * j];
    const float bias = attn_b[i];
    for (int b = 0; b < B_SZ; ++b) {
        const float4* s4 = (const float4*)(state + b * H2D);
        float p = 0.f;
#pragma unroll
        for (int j = 0; j < 4; ++j) p += dot4(r[j], s4[lane + 64 * j]);
#pragma unroll
        for (int off = 32; off; off >>= 1) p += __shfl_xor(p, off, 64);
        if (lane == 0) altered[b * H2D + i] = p + bias;
    }
}

// Single pass over enc (256 MB read ONCE): per-wave online softmax, one rescale
// per 4 rows. Wave slot owns 16 consecutive s. Coalesced lane+64j float4 loads.
__global__ __launch_bounds__(256) void k_flash(const float* __restrict__ enc,
                                               const float* __restrict__ altered,
                                               float* __restrict__ w_raw,
                                               float* __restrict__ pm,
                                               float* __restrict__ pl,
                                               float* __restrict__ pacc) {
    const int b = blockIdx.y;
    const int wave = threadIdx.x >> 6, lane = threadIdx.x & 63;
    const int slot = blockIdx.x * 4 + wave;  // 0..255

    const float4* a4 = (const float4*)(altered + b * H2D);
    float4 af[4];
#pragma unroll
    for (int j = 0; j < 4; ++j) af[j] = a4[lane + 64 * j];

    float m = -1e30f, l = 0.f;
    float4 acc[4];
#pragma unroll
    for (int j = 0; j < 4; ++j) acc[j] = make_float4(0.f, 0.f, 0.f, 0.f);

    const int s0 = slot * 16;
    for (int k = 0; k < 16; k += 4) {
        float4 e[4][4];
        float p[4];
#pragma unroll
        for (int r = 0; r < 4; ++r) {
            const float4* e4 = (const float4*)(enc + ((size_t)(s0 + k + r) * B_SZ + b) * H2D);
#pragma unroll
            for (int j = 0; j < 4; ++j) e[r][j] = e4[lane + 64 * j];
        }
#pragma unroll
        for (int r = 0; r < 4; ++r) {
            p[r] = 0.f;
#pragma unroll
            for (int j = 0; j < 4; ++j) p[r] += dot4(af[j], e[r][j]);
        }
#pragma unroll
        for (int off = 32; off; off >>= 1)
#pragma unroll
            for (int r = 0; r < 4; ++r) p[r] += __shfl_xor(p[r], off, 64);
        if (lane == 0) {
#pragma unroll
            for (int r = 0; r < 4; ++r) w_raw[b * S_LEN + s0 + k + r] = p[r];
        }
        // one online-softmax merge for all 4 rows
        float mn = m;
#pragma unroll
        for (int r = 0; r < 4; ++r) mn = fmaxf(mn, p[r]);
        const float sc = __expf(m - mn);
        float ex[4];
#pragma unroll
        for (int r = 0; r < 4; ++r) ex[r] = __expf(p[r] - mn);
        l = l * sc + ex[0] + ex[1] + ex[2] + ex[3];
#pragma unroll
        for (int j = 0; j < 4; ++j) {
            acc[j].x *= sc; acc[j].y *= sc; acc[j].z *= sc; acc[j].w *= sc;
#pragma unroll
            for (int r = 0; r < 4; ++r) axpy4(acc[j], ex[r], e[r][j]);
        }
        m = mn;
    }

    const size_t pi = (size_t)(b * P_PER_B + slot);
    if (lane == 0) { pm[pi] = m; pl[pi] = l; }
    float4* o = (float4*)(pacc + pi * H2D);
#pragma unroll
    for (int j = 0; j < 4; ++j) o[lane + 64 * j] = acc[j];
}

// Per batch: reduce (m,l) partials -> M, 1/Z; write cexp; normalized weights;
// zero out_attn for the atomic combine. grid B_SZ x 256 thr.
__global__ __launch_bounds__(256) void k_fin1(const float* __restrict__ pm,
                                              const float* __restrict__ pl,
                                              const float* __restrict__ w_raw,
                                              float* __restrict__ cexp,
                                              float* __restrict__ MZ,
                                              float* __restrict__ out_attn,
                                              float* __restrict__ out_nw) {
    const int b = blockIdx.x, t = threadIdx.x;
    const int wave = t >> 6, lane = t & 63;
    __shared__ float sw[4];
    const float mv = pm[b * P_PER_B + t];
    float mm = mv;
#pragma unroll
    for (int off = 32; off; off >>= 1) mm = fmaxf(mm, __shfl_xor(mm, off, 64));
    if (lane == 0) sw[wave] = mm;
    __syncthreads();
    const float M = fmaxf(fmaxf(sw[0], sw[1]), fmaxf(sw[2], sw[3]));
    const float e = __expf(mv - M);
    float zl = e * pl[b * P_PER_B + t];
#pragma unroll
    for (int off = 32; off; off >>= 1) zl += __shfl_xor(zl, off, 64);
    __syncthreads();
    if (lane == 0) sw[wave] = zl;
    __syncthreads();
    const float invZ = 1.f / (sw[0] + sw[1] + sw[2] + sw[3]);
    cexp[b * P_PER_B + t] = e;
    if (t == 0) { MZ[2 * b] = M; MZ[2 * b + 1] = invZ; }
    // zero out_attn row (poisoned 0xAA by harness; k_fin2 atomically accumulates)
    ((float4*)(out_attn + b * H2D))[t] = make_float4(0.f, 0.f, 0.f, 0.f);
    // normalized weights
    const float4* wr = (const float4*)(w_raw + b * S_LEN);
    float4* on = (float4*)(out_nw + b * S_LEN);
#pragma unroll
    for (int i = 0; i < 4; ++i) {
        const int idx = t + 256 * i;
        const float4 v = wr[idx];
        on[idx] = make_float4(__expf(v.x - M) * invZ, __expf(v.y - M) * invZ,
                              __expf(v.z - M) * invZ, __expf(v.w - M) * invZ);
    }
}

// Combine: out_attn[b][d] += invZ * sum_{p in group} cexp[p]*pacc[b][p][d].
// grid (B_SZ, 4); each block handles 64 partials; thread t = float4 col.
__global__ __launch_bounds__(256) void k_fin2(const float* __restrict__ pacc,
                                              const float* __restrict__ cexp,
                                              const float* __restrict__ MZ,
                                              float* __restrict__ out_attn) {
    const int b = blockIdx.x, pg = blockIdx.y, t = threadIdx.x;
    const float invZ = MZ[2 * b + 1];
    const float* cb = cexp + b * P_PER_B + pg * 64;
    const float4* base = (const float4*)(pacc + (size_t)(b * P_PER_B + pg * 64) * H2D);
    float4 s = make_float4(0.f, 0.f, 0.f, 0.f);
#pragma unroll 8
    for (int p = 0; p < 64; ++p) {
        const float c = cb[p];
        axpy4(s, c, base[(size_t)p * 256 + t]);
    }
    float* o = out_attn + b * H2D + 4 * t;
    atomicAdd(o + 0, s.x * invZ);
    atomicAdd(o + 1, s.y * invZ);
    atomicAdd(o + 2, s.z * invZ);
    atomicAdd(o + 3, s.w * invZ);
}

extern "C" void kernel_launch(void* const* d_in, const int* in_sizes, int n_in,
                              void* d_out, int out_size, void* d_ws, size_t ws_size,
                              hipStream_t stream) {
    const float* enc    = (const float*)d_in[0];  // [S, B, 2H]
    const float* state  = (const float*)d_in[1];  // [B, 2H]
    // d_in[2] previous_attention, d_in[5] time_w, d_in[6] time_b: dead branch, unused
    const float* attn_w = (const float*)d_in[3];  // [2H, 2H]
    const float* attn_b = (const float*)d_in[4];  // [2H]

    float* ws = (float*)d_ws;
    float* altered = ws;                   // 16384 floats
    float* w_raw   = altered + 16384;      // 65536
    float* pm      = w_raw + 65536;        // 4096
    float* pl      = pm + 4096;            // 4096
    float* cexp    = pl + 4096;            // 4096
    float* MZ      = cexp + 4096;          // 32 (padded 1024)
    float* pacc    = MZ + 1024;            // 16*256*1024 floats (16 MB)

    float* out_attn = (float*)d_out;               // [B, 2H]
    float* out_nw   = (float*)d_out + B_SZ * H2D;  // [B, S]

    hipLaunchKernelGGL(k_altered, dim3(256), dim3(256), 0, stream,
                       state, attn_w, attn_b, altered);
    hipLaunchKernelGGL(k_flash, dim3(64, B_SZ), dim3(256), 0, stream,
                       enc, altered, w_raw, pm, pl, pacc);
    hipLaunchKernelGGL(k_fin1, dim3(B_SZ), dim3(256), 0, stream,
                       pm, pl, w_raw, cexp, MZ, out_attn, out_nw);
    hipLaunchKernelGGL(k_fin2, dim3(B_SZ, 4), dim3(256), 0, stream,
                       pacc, cexp, MZ, out_attn);
}

// Round 4
// 408.991 us; speedup vs baseline: 1.1002x; 1.0167x over previous
//
#include <hip/hip_runtime.h>
#include <cstdint>
#include <cstddef>

#define S_LEN 4096
#define B_SZ 16
#define H2D 1024
#define P_PER_B 128     // one partial per wave-slot per batch (32 s-rows each)

__device__ __forceinline__ float dot4(float4 a, float4 b) {
    return a.x * b.x + a.y * b.y + a.z * b.z + a.w * b.w;
}
__device__ __forceinline__ void axpy4(float4& acc, float w, float4 v) {
    acc.x += w * v.x; acc.y += w * v.y; acc.z += w * v.z; acc.w += w * v.w;
}

// altered[b][i] = attn_b[i] + sum_j state[b][j]*attn_w[i][j]; one wave per row i.
__global__ __launch_bounds__(256) void k_altered(const float* __restrict__ state,
                                                 const float* __restrict__ attn_w,
                                                 const float* __restrict__ attn_b,
                                                 float* __restrict__ altered) {
    const int i = (blockIdx.x * 256 + threadIdx.x) >> 6;  // 0..1023
    const int lane = threadIdx.x & 63;
    const float4* w4 = (const float4*)(attn_w + (size_t)i * H2D);
    float4 r[4];
#pragma unroll
    for (int j = 0; j < 4; ++j) r[j] = w4[lane + 64 * j];
    const float bias = attn_b[i];
    for (int b = 0; b < B_SZ; ++b) {
        const float4* s4 = (const float4*)(state + b * H2D);
        float p = 0.f;
#pragma unroll
        for (int j = 0; j < 4; ++j) p += dot4(r[j], s4[lane + 64 * j]);
#pragma unroll
        for (int off = 32; off; off >>= 1) p += __shfl_xor(p, off, 64);
        if (lane == 0) altered[b * H2D + i] = p + bias;
    }
}

// Single pass over enc (256 MB read ONCE): per-wave online softmax, one rescale
// per 4 rows. Wave slot owns 32 consecutive s. Coalesced lane+64j float4 loads.
__global__ __launch_bounds__(256) void k_flash(const float* __restrict__ enc,
                                               const float* __restrict__ altered,
                                               float* __restrict__ w_raw,
                                               float* __restrict__ pm,
                                               float* __restrict__ pl,
                                               float* __restrict__ pacc) {
    const int b = blockIdx.y;
    const int wave = threadIdx.x >> 6, lane = threadIdx.x & 63;
    const int slot = blockIdx.x * 4 + wave;  // 0..127

    const float4* a4 = (const float4*)(altered + b * H2D);
    float4 af[4];
#pragma unroll
    for (int j = 0; j < 4; ++j) af[j] = a4[lane + 64 * j];

    float m = -1e30f, l = 0.f;
    float4 acc[4];
#pragma unroll
    for (int j = 0; j < 4; ++j) acc[j] = make_float4(0.f, 0.f, 0.f, 0.f);

    const int s0 = slot * 32;
    for (int k = 0; k < 32; k += 4) {
        float4 e[4][4];
        float p[4];
#pragma unroll
        for (int r = 0; r < 4; ++r) {
            const float4* e4 = (const float4*)(enc + ((size_t)(s0 + k + r) * B_SZ + b) * H2D);
#pragma unroll
            for (int j = 0; j < 4; ++j) e[r][j] = e4[lane + 64 * j];
        }
#pragma unroll
        for (int r = 0; r < 4; ++r) {
            p[r] = 0.f;
#pragma unroll
            for (int j = 0; j < 4; ++j) p[r] += dot4(af[j], e[r][j]);
        }
#pragma unroll
        for (int off = 32; off; off >>= 1)
#pragma unroll
            for (int r = 0; r < 4; ++r) p[r] += __shfl_xor(p[r], off, 64);
        if (lane == 0) {
#pragma unroll
            for (int r = 0; r < 4; ++r) w_raw[b * S_LEN + s0 + k + r] = p[r];
        }
        // one online-softmax merge for all 4 rows
        float mn = m;
#pragma unroll
        for (int r = 0; r < 4; ++r) mn = fmaxf(mn, p[r]);
        const float sc = __expf(m - mn);
        float ex[4];
#pragma unroll
        for (int r = 0; r < 4; ++r) ex[r] = __expf(p[r] - mn);
        l = l * sc + ex[0] + ex[1] + ex[2] + ex[3];
#pragma unroll
        for (int j = 0; j < 4; ++j) {
            acc[j].x *= sc; acc[j].y *= sc; acc[j].z *= sc; acc[j].w *= sc;
#pragma unroll
            for (int r = 0; r < 4; ++r) axpy4(acc[j], ex[r], e[r][j]);
        }
        m = mn;
    }

    const size_t pi = (size_t)(b * P_PER_B + slot);
    if (lane == 0) { pm[pi] = m; pl[pi] = l; }
    float4* o = (float4*)(pacc + pi * H2D);
#pragma unroll
    for (int j = 0; j < 4; ++j) o[lane + 64 * j] = acc[j];
}

// Per batch: reduce 128 (m,l) partials -> M, 1/Z; write cexp; normalized
// weights; zero out_attn for the atomic combine. grid B_SZ x 256 thr.
__global__ __launch_bounds__(256) void k_fin1(const float* __restrict__ pm,
                                              const float* __restrict__ pl,
                                              const float* __restrict__ w_raw,
                                              float* __restrict__ cexp,
                                              float* __restrict__ MZ,
                                              float* __restrict__ out_attn,
                                              float* __restrict__ out_nw) {
    const int b = blockIdx.x, t = threadIdx.x;
    const int wave = t >> 6, lane = t & 63;
    __shared__ float sw[4];
    const float mv = (t < P_PER_B) ? pm[b * P_PER_B + t] : -1e30f;
    float mm = mv;
#pragma unroll
    for (int off = 32; off; off >>= 1) mm = fmaxf(mm, __shfl_xor(mm, off, 64));
    if (lane == 0) sw[wave] = mm;
    __syncthreads();
    const float M = fmaxf(fmaxf(sw[0], sw[1]), fmaxf(sw[2], sw[3]));
    const float e = (t < P_PER_B) ? __expf(mv - M) : 0.f;
    float zl = (t < P_PER_B) ? e * pl[b * P_PER_B + t] : 0.f;
#pragma unroll
    for (int off = 32; off; off >>= 1) zl += __shfl_xor(zl, off, 64);
    __syncthreads();
    if (lane == 0) sw[wave] = zl;
    __syncthreads();
    const float invZ = 1.f / (sw[0] + sw[1] + sw[2] + sw[3]);
    if (t < P_PER_B) cexp[b * P_PER_B + t] = e;
    if (t == 0) { MZ[2 * b] = M; MZ[2 * b + 1] = invZ; }
    // zero out_attn row (poisoned 0xAA by harness; k_fin2 atomically accumulates)
    ((float4*)(out_attn + b * H2D))[t] = make_float4(0.f, 0.f, 0.f, 0.f);
    // normalized weights
    const float4* wr = (const float4*)(w_raw + b * S_LEN);
    float4* on = (float4*)(out_nw + b * S_LEN);
#pragma unroll
    for (int i = 0; i < 4; ++i) {
        const int idx = t + 256 * i;
        const float4 v = wr[idx];
        on[idx] = make_float4(__expf(v.x - M) * invZ, __expf(v.y - M) * invZ,
                              __expf(v.z - M) * invZ, __expf(v.w - M) * invZ);
    }
}

// Combine: out_attn[b][d] += invZ * sum_{p in group} cexp[p]*pacc[b][p][d].
// grid (B_SZ, 2); each block handles 64 partials; thread t = float4 col.
__global__ __launch_bounds__(256) void k_fin2(const float* __restrict__ pacc,
                                              const float* __restrict__ cexp,
                                              const float* __restrict__ MZ,
                                              float* __restrict__ out_attn) {
    const int b = blockIdx.x, pg = blockIdx.y, t = threadIdx.x;
    const float invZ = MZ[2 * b + 1];
    const float* cb = cexp + b * P_PER_B + pg * 64;
    const float4* base = (const float4*)(pacc + (size_t)(b * P_PER_B + pg * 64) * H2D);
    float4 s = make_float4(0.f, 0.f, 0.f, 0.f);
#pragma unroll 8
    for (int p = 0; p < 64; ++p) {
        const float c = cb[p];
        axpy4(s, c, base[(size_t)p * 256 + t]);
    }
    float* o = out_attn + b * H2D + 4 * t;
    atomicAdd(o + 0, s.x * invZ);
    atomicAdd(o + 1, s.y * invZ);
    atomicAdd(o + 2, s.z * invZ);
    atomicAdd(o + 3, s.w * invZ);
}

extern "C" void kernel_launch(void* const* d_in, const int* in_sizes, int n_in,
                              void* d_out, int out_size, void* d_ws, size_t ws_size,
                              hipStream_t stream) {
    const float* enc    = (const float*)d_in[0];  // [S, B, 2H]
    const float* state  = (const float*)d_in[1];  // [B, 2H]
    // d_in[2] previous_attention, d_in[5] time_w, d_in[6] time_b: dead branch, unused
    const float* attn_w = (const float*)d_in[3];  // [2H, 2H]
    const float* attn_b = (const float*)d_in[4];  // [2H]

    float* ws = (float*)d_ws;
    float* altered = ws;                   // 16384 floats
    float* w_raw   = altered + 16384;      // 65536
    float* pm      = w_raw + 65536;        // 2048
    float* pl      = pm + 2048;            // 2048
    float* cexp    = pl + 2048;            // 2048
    float* MZ      = cexp + 2048;          // 32 (padded 1024)
    float* pacc    = MZ + 1024;            // 16*128*1024 floats (8 MB)

    float* out_attn = (float*)d_out;               // [B, 2H]
    float* out_nw   = (float*)d_out + B_SZ * H2D;  // [B, S]

    hipLaunchKernelGGL(k_altered, dim3(256), dim3(256), 0, stream,
                       state, attn_w, attn_b, altered);
    hipLaunchKernelGGL(k_flash, dim3(32, B_SZ), dim3(256), 0, stream,
                       enc, altered, w_raw, pm, pl, pacc);
    hipLaunchKernelGGL(k_fin1, dim3(B_SZ), dim3(256), 0, stream,
                       pm, pl, w_raw, cexp, MZ, out_attn, out_nw);
    hipLaunchKernelGGL(k_fin2, dim3(B_SZ, 2), dim3(256), 0, stream,
                       pacc, cexp, MZ, out_attn);
}